// Round 4
// baseline (200.814 us; speedup 1.0000x reference)
//
#include <hip/hip_runtime.h>
#include <hip/hip_bf16.h>
#include <cmath>

typedef float f32x16 __attribute__((ext_vector_type(16)));
typedef __bf16 bf16x8 __attribute__((ext_vector_type(8)));
typedef __bf16 bf16x4 __attribute__((ext_vector_type(4)));

#define NE 8
#define H 1024
#define DF 2048
#define WCOLS 16384
#define NTOK 4096
#define MROWS 8192
#define NBLK 64

// Wt layout: 64 super-tiles (e*8 + bxp), bxp = 256-col panel. Within:
//   idx = ((e*8+bxp)*32 + kb)*8192 + grp*1024 + chunk*256 + row*8 + j
//   col = bxp*256 + grp*32 + row ; k = kb*32 + chunk*8 + j
// i.e. every 16B of Wt = 8 k-consecutive elems of one w1 column — the exact
// MFMA fragment image. GEMM stages it with linear global_load_lds copies and
// reads fragments as contiguous 1KB/wave (zero bank conflicts).

typedef const __attribute__((address_space(1))) unsigned int glb_u32;
typedef __attribute__((address_space(3))) unsigned int lds_u32;

__device__ __forceinline__ void async_load16(const void* g, void* l) {
    __builtin_amdgcn_global_load_lds((glb_u32*)g, (lds_u32*)l, 16, 0, 0);
}

// ---------------- kernel 1: router + x->bf16 (1024 blocks) ------------------
__global__ __launch_bounds__(256) void router_kernel(
    const float* __restrict__ x, const float* __restrict__ rw,
    float* __restrict__ logits, int* __restrict__ sel, float* __restrict__ rwn,
    __bf16* __restrict__ xb)
{
    int b = blockIdx.x;
    int tid = threadIdx.x;
    int tok  = b * 4 + (tid >> 6);
    int lane = tid & 63;
    const float* xr = x + (size_t)tok * H;
    __bf16* xbr = xb + (size_t)tok * H;
    float acc[NE];
#pragma unroll
    for (int e = 0; e < NE; ++e) acc[e] = 0.f;
#pragma unroll
    for (int it = 0; it < 4; ++it) {
        int k = (it * 64 + lane) * 4;
        float4 xv = *(const float4*)(xr + k);
        bf16x4 xc;
        xc[0] = (__bf16)xv.x; xc[1] = (__bf16)xv.y;
        xc[2] = (__bf16)xv.z; xc[3] = (__bf16)xv.w;
        *(bf16x4*)(xbr + k) = xc;
#pragma unroll
        for (int e = 0; e < NE; ++e) {
            float4 wv = *(const float4*)(rw + e * H + k);
            acc[e] += xv.x * wv.x + xv.y * wv.y + xv.z * wv.z + xv.w * wv.w;
        }
    }
#pragma unroll
    for (int e = 0; e < NE; ++e) {
        float v = acc[e];
#pragma unroll
        for (int off = 32; off > 0; off >>= 1) v += __shfl_xor(v, off, 64);
        acc[e] = v;
    }
    if (lane == 0) {
#pragma unroll
        for (int e = 0; e < NE; ++e) logits[tok * NE + e] = acc[e];
        int i1 = 0; float m1 = acc[0];
#pragma unroll
        for (int e = 1; e < NE; ++e) if (acc[e] > m1) { m1 = acc[e]; i1 = e; }
        int i2 = -1; float m2 = -INFINITY;
#pragma unroll
        for (int e = 0; e < NE; ++e) if (e != i1 && acc[e] > m2) { m2 = acc[e]; i2 = e; }
        float e2 = expf(m2 - m1);
        float inv = 1.f / (1.f + e2);
        sel[tok * 2]     = i1;  sel[tok * 2 + 1] = i2;
        rwn[tok * 2]     = inv; rwn[tok * 2 + 1] = e2 * inv;
    }
}

// ------ kernel 2: blocks [0,8192) = direct-gather transpose (no LDS);
// ------           block 8192 = counting sort (runs concurrently, hidden) ----
__global__ __launch_bounds__(256) void mid_kernel(
    const float* __restrict__ w1, __bf16* __restrict__ Wt,
    const int* __restrict__ sel, const float* __restrict__ rwn,
    int* __restrict__ stok, float* __restrict__ srw, int* __restrict__ bexp)
{
    __shared__ int cnt[NE][256];
    __shared__ int wtot[NE];
    __shared__ int ebase[NE + 1];
    int b = blockIdx.x;
    int t = threadIdx.x;

    if (b < 8192) {
        // one thread -> one 16B Wt fragment = 8 strided f32 from one column.
        // Wave: per load j, lanes 0-31 / 32-63 read two 128B segments (coalesced);
        // store is 1KB contiguous per wave.
        int q = b * 256 + t;                   // fragment index, 0..2M
        int row   = q & 31;
        int chunk = (q >> 5) & 3;
        int grp   = (q >> 7) & 7;
        int kb    = (q >> 10) & 31;
        int ep    = q >> 15;                   // e*8+bxp, 0..63
        int col   = ep * 256 + grp * 32 + row;
        int k0    = kb * 32 + chunk * 8;
        const float* src = w1 + (size_t)k0 * WCOLS + col;
        bf16x8 o;
#pragma unroll
        for (int j = 0; j < 8; ++j) o[j] = (__bf16)src[(size_t)j * WCOLS];
        *(bf16x8*)(Wt + (size_t)q * 8) = o;
        return;
    }

    // ---------------- sort: 256 threads, 32 items each ----------------
    int selv[32];
    int lc[NE];
#pragma unroll
    for (int e = 0; e < NE; ++e) lc[e] = 0;
    int base = t * 32;
#pragma unroll
    for (int j = 0; j < 32; ++j) { selv[j] = sel[base + j]; lc[selv[j]]++; }
#pragma unroll
    for (int e = 0; e < NE; ++e) cnt[e][t] = lc[e];
    __syncthreads();
    // scan: wave w handles experts {2w, 2w+1}; lane l owns cnt[e][4l..4l+4)
    int l = t & 63;
#pragma unroll
    for (int ee = 0; ee < 2; ++ee) {
        int e = (t >> 6) * 2 + ee;
        int s = 0, pre[4];
#pragma unroll
        for (int i = 0; i < 4; ++i) { pre[i] = s; s += cnt[e][l * 4 + i]; }
        int inc = s;
#pragma unroll
        for (int d = 1; d < 64; d <<= 1) {
            int v = __shfl_up(inc, d, 64);
            if (l >= d) inc += v;
        }
        if (l == 63) wtot[e] = inc;
        int excl = inc - s;
#pragma unroll
        for (int i = 0; i < 4; ++i) cnt[e][l * 4 + i] = excl + pre[i];
    }
    __syncthreads();
    if (t == 0) {
        int acc = 0;
        for (int e = 0; e < NE; ++e) { ebase[e] = acc; acc += wtot[e]; }
        ebase[NE] = acc;
    }
    __syncthreads();
    int off[NE];
#pragma unroll
    for (int e = 0; e < NE; ++e) off[e] = ebase[e] + cnt[e][t];
#pragma unroll
    for (int j = 0; j < 32; ++j) {
        int i = base + j;
        int e = selv[j];
        int pos = off[e]++;
        stok[pos] = i >> 1;
        srw[pos]  = rwn[i];
    }
    __syncthreads();
    if (t < NBLK) {
        int r = t * 128;
        int e = 0;
        while (e < NE - 1 && r >= ebase[e + 1]) ++e;
        bexp[t] = e;
    }
}

// ---- kernel 3: GEMM. 128x128 tile, 4 waves x (64x64), BK=16,
// ---- 3x8KB buffers (25KB LDS -> 4 blocks/CU), counted vmcnt depth-2 --------
__global__ __launch_bounds__(256, 4) void moe_gemm(
    const __bf16* __restrict__ xb, const __bf16* __restrict__ Wt,
    const int* __restrict__ stok, const float* __restrict__ srw,
    const int* __restrict__ bexp, float* __restrict__ out)
{
    // buffer bb (4096 elems = 8KB): A [0,2048) = [grp4][chunk2][row32][8]
    //                               B [2048,4096) = [grp4][chunk2][row32][8]
    __shared__ __align__(16) __bf16 smem[3 * 4096];
    __shared__ int   tokS[128];
    __shared__ float rwS[128];

    int g = blockIdx.x;                        // 1024 blocks
    int by = (g & 7) * 8 + ((g >> 3) & 7);     // 0..63 (XCD swizzle)
    int bx = g >> 6;                           // 0..15 (128-col tiles)
    int tid = threadIdx.x;
    if (tid < 128) {
        tokS[tid] = stok[by * 128 + tid];
        rwS[tid]  = srw[by * 128 + tid];
    }
    int e = bexp[by];
    __syncthreads();

    int lane = tid & 63;
    int wv   = tid >> 6;
    int l32  = lane & 31;
    int hi   = lane >> 5;

    // A staging: thread t -> A slot (grp=t>>6, chunk=(t>>5)&1, row=t&31)
    const __bf16* aSrcT = xb + (size_t)tokS[(tid >> 6) * 32 + (tid & 31)] * H
                             + ((tid >> 5) & 1) * 8;
    // B staging: thread t -> B slot obl=t*8; src grp = (bx&1)*4 + (t>>6)
    const __bf16* bSrcT = Wt + (size_t)(e * 8 + (bx >> 1)) * 262144
                             + ((bx & 1) * 4 + (tid >> 6)) * 1024
                             + ((tid * 8) & 511);
    __bf16* aDst = smem + tid * 8;
    __bf16* bDst = smem + 2048 + tid * 8;

#define STAGE(kt_, bb_) do {                                                   \
        int koff_ = (((kt_) >> 1) << 13) + (((kt_) & 1) << 9);                 \
        async_load16(aSrcT + (kt_) * 16, aDst + (bb_) * 4096);                 \
        async_load16(bSrcT + koff_,      bDst + (bb_) * 4096);                 \
    } while (0)

    int wm = (wv & 1) * 64;
    int wn = (wv >> 1) * 64;
    int agb = (wv & 1) * 2;                    // A group base
    int bgb = (wv >> 1) * 2;                   // B group base
    int rdo = hi * 256 + l32 * 8;

    f32x16 acc[2][2];
#pragma unroll
    for (int i = 0; i < 2; ++i)
#pragma unroll
        for (int j = 0; j < 2; ++j)
#pragma unroll
            for (int r = 0; r < 16; ++r) acc[i][j][r] = 0.f;

    // prologue: stage K-tiles 0,1 (4 loads/thread in flight)
    STAGE(0, 0);
    STAGE(1, 1);

    int cur = 0;
    for (int kt = 0; kt < 64; ++kt) {
        // complete exactly tile kt's 2 loads; keep kt+1's 2 in flight
        if (kt < 63) asm volatile("s_waitcnt vmcnt(2)" ::: "memory");
        else         asm volatile("s_waitcnt vmcnt(0)" ::: "memory");
        __builtin_amdgcn_s_barrier();          // publish tile kt
        __builtin_amdgcn_sched_barrier(0);
        int nb = cur + 2; if (nb >= 3) nb -= 3;
        if (kt < 62) STAGE(kt + 2, nb);        // refill buffer freed at kt-1

        const __bf16* Ab = smem + cur * 4096;
        bf16x8 af[2], bfr[2];
#pragma unroll
        for (int ti = 0; ti < 2; ++ti)
            af[ti]  = *(const bf16x8*)&Ab[(agb + ti) * 512 + rdo];
#pragma unroll
        for (int tj = 0; tj < 2; ++tj)
            bfr[tj] = *(const bf16x8*)&Ab[2048 + (bgb + tj) * 512 + rdo];

        __builtin_amdgcn_s_setprio(1);
#pragma unroll
        for (int ti = 0; ti < 2; ++ti)
#pragma unroll
            for (int tj = 0; tj < 2; ++tj)
                acc[ti][tj] = __builtin_amdgcn_mfma_f32_32x32x16_bf16(
                    af[ti], bfr[tj], acc[ti][tj], 0, 0, 0);
        __builtin_amdgcn_s_setprio(0);

        cur = cur + 1; if (cur >= 3) cur -= 3;
    }
#undef STAGE

    // epilogue: gelu (tanh form) * rw; C/D: row=(reg&3)+8*(reg>>2)+4*hi, col=l32
    int rowh = hi * 4;
#pragma unroll
    for (int ti = 0; ti < 2; ++ti)
#pragma unroll
        for (int reg = 0; reg < 16; ++reg) {
            int row = (reg & 3) + 8 * (reg >> 2) + rowh;
            int m = wm + ti * 32 + row;
            float rw = rwS[m];
            size_t ob = (size_t)(by * 128 + m) * DF + bx * 128 + wn + l32;
#pragma unroll
            for (int tj = 0; tj < 2; ++tj) {
                float val = acc[ti][tj][reg];
                float u = 0.7978845608028654f * val * (1.f + 0.044715f * val * val);
                float t = __expf(-2.f * fabsf(u));
                float th = (1.f - t) / (1.f + t);
                th = u < 0.f ? -th : th;
                out[ob + tj * 32] = 0.5f * val * (1.f + th) * rw;
            }
        }
}

extern "C" void kernel_launch(void* const* d_in, const int* in_sizes, int n_in,
                              void* d_out, int out_size, void* d_ws, size_t ws_size,
                              hipStream_t stream) {
    (void)in_sizes; (void)n_in; (void)out_size; (void)ws_size;
    const float* x        = (const float*)d_in[0];
    const float* router_w = (const float*)d_in[1];
    const float* w1       = (const float*)d_in[2];
    float* out    = (float*)d_out;
    float* logits = out + (size_t)MROWS * DF;

    char* ws    = (char*)d_ws;
    int*   sel  = (int*)(ws);
    float* rwn  = (float*)(ws + 0x8000);
    int*   stok = (int*)(ws + 0x10000);
    float* srw  = (float*)(ws + 0x18000);
    int*   bexp = (int*)(ws + 0x20000);
    __bf16* xb  = (__bf16*)(ws + (1 << 20));             // 8 MB
    __bf16* Wt  = (__bf16*)(ws + (1 << 20) + (8 << 20)); // 32 MB

    router_kernel<<<1024, 256, 0, stream>>>(x, router_w, logits, sel, rwn, xb);
    mid_kernel<<<8193, 256, 0, stream>>>(w1, Wt, sel, rwn, stok, srw, bexp);
    moe_gemm<<<1024, 256, 0, stream>>>(xb, Wt, stok, srw, bexp, out);
}